// Round 6
// baseline (493.374 us; speedup 1.0000x reference)
//
#include <hip/hip_runtime.h>
#include <hip/hip_bf16.h>

// ---------------- problem constants (fixed by setup_inputs) ----------------
#define NUM_B   16
#define DIM     512
#define TT      1500
#define NROWS   (NUM_B * TT)              // 24000
#define NCODES  4096
#define ROW_TILES ((NROWS + 127) / 128)   // 188
#define NROWS_PAD (ROW_TILES * 128)       // 24064
#define NSLICE  8                         // partial cd slices (atomic decontention)
#define SHIFTC  30.0f                     // exp shift: exp(SHIFT-d), cancels in softmax
#define NBLKX   (NCODES / 128)            // 32 col tiles
#define TBLKS   (NUM_B * 47)              // 752 transpose blocks (47 t-tiles of 32)
#define CBLKS   (NCODES / 4)              // 1024 cb blocks
#define NZERO   (NROWS_PAD + NSLICE * NCODES)   // Sg + cdp
#define NZERO2  (NZERO + 1)               // + tot scalar
#define NZERO3  (NZERO2 + ROW_TILES)      // + per-panel completion counters

typedef __bf16 bf16x8 __attribute__((ext_vector_type(8)));
typedef float  floatx4 __attribute__((ext_vector_type(4)));
typedef unsigned short ushortx8 __attribute__((ext_vector_type(8)));

// async global->LDS, 16B per lane; dest = wave-uniform base + lane*16
__device__ __forceinline__ void glds16(const void* g, void* l) {
    __builtin_amdgcn_global_load_lds(
        (__attribute__((address_space(1))) void*)(void*)g,
        (__attribute__((address_space(3))) void*)l, 16, 0, 0);
}

// ---------------- prep: transpose + z2 (register-accum) + cb + ws zeroing -------
__global__ __launch_bounds__(256) void k_prep(
    const float* __restrict__ sf, const float* __restrict__ cb,
    unsigned short* __restrict__ zbf, unsigned short* __restrict__ cbbf,
    float* __restrict__ z2, float* __restrict__ c2, float* __restrict__ zero0,
    float* __restrict__ outp) {
    int id = blockIdx.x, tid = threadIdx.x;
    if (id < TBLKS) {
        __shared__ float tile[32][257];
        int b = id / 47, t0 = (id % 47) * 32;
        int tl = tid & 31, dg = tid >> 5;       // phase 1: t lane, d group (8x32)
        int tr = tid >> 3, dgr = tid & 7;       // phase 2: 8 lanes per t-row
        int tg = t0 + tr;
        float ssq = 0.f;
        unsigned short* dst = zbf + (size_t)(b * TT + tg) * DIM;
#pragma unroll
        for (int half = 0; half < 2; ++half) {
            int dbase = half * 256;
            if (half) __syncthreads();          // drain phase-2 reads of prev half
            int t = t0 + tl;
            if (t < TT) {
                const float* src = sf + (size_t)(b * DIM + dbase + dg * 32) * TT + t;
#pragma unroll
                for (int k = 0; k < 32; ++k)
                    tile[tl][dg * 32 + k] = src[(size_t)k * TT];
            }
            __syncthreads();
            if (tg < TT) {
#pragma unroll
                for (int seg = 0; seg < 4; ++seg) {
                    int d0 = seg * 64 + dgr * 8;
                    unsigned int h[8];
#pragma unroll
                    for (int i2 = 0; i2 < 8; ++i2) {
                        __hip_bfloat16 hb = __float2bfloat16(tile[tr][d0 + i2]);
                        h[i2] = __builtin_bit_cast(unsigned short, hb);
                        float vb = __bfloat162float(hb);
                        ssq += vb * vb;
                    }
                    uint4 o;
                    o.x = h[0] | (h[1] << 16); o.y = h[2] | (h[3] << 16);
                    o.z = h[4] | (h[5] << 16); o.w = h[6] | (h[7] << 16);
                    *(uint4*)(dst + dbase + d0) = o;
                }
            }
        }
        // reduce over the 8 lanes sharing tr (lane bits 0..2)
        ssq += __shfl_xor(ssq, 1); ssq += __shfl_xor(ssq, 2); ssq += __shfl_xor(ssq, 4);
        if (dgr == 0 && tg < TT) z2[b * TT + tg] = ssq;
    } else {
        int ci = id - TBLKS;
        int gid = ci * 256 + tid;
        if (gid < NZERO3) zero0[gid] = 0.f;     // Sg + cdp + tot + panel counters
        if (ci == 0 && tid == 0) outp[0] = 1.0f;
        int k = ci * 4 + (tid >> 6);
        int lane = tid & 63;
        const float4* src = (const float4*)(cb + (size_t)k * DIM + lane * 8);
        float4 a = src[0], b2 = src[1];
        float vals[8] = {a.x, a.y, a.z, a.w, b2.x, b2.y, b2.z, b2.w};
        float s = 0.f;
        unsigned int h[8];
#pragma unroll
        for (int i = 0; i < 8; ++i) {
            __hip_bfloat16 hb = __float2bfloat16(vals[i]);
            h[i] = __builtin_bit_cast(unsigned short, hb);
            float vb = __bfloat162float(hb);
            s += vb * vb;
        }
        uint4 o;
        o.x = h[0] | (h[1] << 16); o.y = h[2] | (h[3] << 16);
        o.z = h[4] | (h[5] << 16); o.w = h[6] | (h[7] << 16);
        *(uint4*)(cbbf + (size_t)k * DIM + lane * 8) = o;
#pragma unroll
        for (int off = 32; off >= 1; off >>= 1) s += __shfl_down(s, off);
        if (lane == 0) c2[k] = s;
    }
}

// ---------------- pass 1: GEMM + exp + FUSED panel scan -------------------------
// Proven 128x128 2-phase MFMA structure (swapped operands -> packed 8B E stores).
// After the epilogue, each block release-fences and bumps a per-row-panel
// counter (device atomics, Guideline 16). The 32nd block of a panel acquires
// and scans the completed 128x4096 E panel (L3-resident) into cdp -- the
// standalone k_scan kernel (98 MB HBM re-read) is eliminated; panel scans
// overlap other blocks' GEMM work.
// Swapped C/D layout: row (n) = wr + 16*i + (lane&15)
//                     col (k) = wc + 16*j + (lane>>4)*4 + reg
__global__ __launch_bounds__(256, 2) void k_gemm1(
    const unsigned short* __restrict__ zbf, const unsigned short* __restrict__ cbbf,
    const float* __restrict__ z2, const float* __restrict__ c2,
    const int* __restrict__ lengths, const int* __restrict__ stride_p,
    float* __restrict__ Sg, unsigned short* __restrict__ Eg,
    int* __restrict__ pcnt, float* __restrict__ cdp) {
    __shared__ unsigned short As[128 * 64];
    __shared__ unsigned short Bs[128 * 64];
    __shared__ float z2s[128], c2s[128];
    __shared__ unsigned char vldp[128];
    __shared__ int s_any;
    __shared__ int s_old;
    __shared__ float rsL[128];
    __shared__ unsigned char vrL[128];
    __shared__ int wcnt[2];
    int tid = threadIdx.x;
    int r0 = blockIdx.y * 128, c0 = blockIdx.x * 128;
    if (tid == 0) s_any = 0;
    __syncthreads();
    if (tid < 128) {
        int n = r0 + tid;
        int valid = 0;
        if (n < NROWS) {
            int b = n / TT, t = n - b * TT;
            int stride = stride_p[0];
            int nv = lengths[b] / stride;
            if (nv > TT) nv = TT;
            valid = (t < nv);
        }
        if (valid) atomicOr(&s_any, 1);
        vldp[tid] = (unsigned char)valid;
        z2s[tid] = z2[r0 + tid];
        c2s[tid] = c2[c0 + tid];
    }
    __syncthreads();
    if (!s_any) return;   // fully-masked panel: no E, no Sg, counter never hits 32

    int wave = tid >> 6, lane = tid & 63;
    int l15 = lane & 15, l4 = lane >> 4;
    int wr = (wave >> 1) * 64, wc = (wave & 1) * 64;

    int srow = lane >> 3;
    int scg = (lane & 7) ^ srow;
    const unsigned short* ag = zbf + (size_t)(r0 + wave * 32 + srow) * DIM + scg * 8;
    const unsigned short* bg = cbbf + (size_t)(c0 + wave * 32 + srow) * DIM + scg * 8;
    unsigned short* al = As + (wave * 32) * 64;
    unsigned short* bl = Bs + (wave * 32) * 64;

    floatx4 acc[4][4];
    const floatx4 zero = {0.f, 0.f, 0.f, 0.f};
#pragma unroll
    for (int i = 0; i < 4; ++i)
#pragma unroll
        for (int j = 0; j < 4; ++j) acc[i][j] = zero;

    int sw = l15 & 7;

    for (int kc = 0; kc < 8; ++kc) {
#pragma unroll
        for (int q = 0; q < 4; ++q) {
            glds16(ag + (size_t)q * 8 * DIM + kc * 64, al + q * 8 * 64);
            glds16(bg + (size_t)q * 8 * DIM + kc * 64, bl + q * 8 * 64);
        }
        __syncthreads();
#pragma unroll
        for (int ks = 0; ks < 64; ks += 32) {
            int g = (ks >> 3) + l4;
            int pcg = g ^ sw;
            bf16x8 av[4], bv[4];
#pragma unroll
            for (int i = 0; i < 4; ++i)
                av[i] = __builtin_bit_cast(bf16x8,
                    *(const ushortx8*)&As[(wr + 16 * i + l15) * 64 + pcg * 8]);
#pragma unroll
            for (int j = 0; j < 4; ++j)
                bv[j] = __builtin_bit_cast(bf16x8,
                    *(const ushortx8*)&Bs[(wc + 16 * j + l15) * 64 + pcg * 8]);
#pragma unroll
            for (int i = 0; i < 4; ++i)
#pragma unroll
                for (int j = 0; j < 4; ++j)
                    acc[i][j] = __builtin_amdgcn_mfma_f32_16x16x32_bf16(bv[j], av[i], acc[i][j], 0, 0, 0);
        }
        __syncthreads();
    }

    // epilogue: e = exp(SHIFT - sqrt(z2+c2-2*dot)); S += row-sum; E[n][k] packed 8B
    float c2r[4][4];
#pragma unroll
    for (int j = 0; j < 4; ++j)
#pragma unroll
        for (int r = 0; r < 4; ++r)
            c2r[j][r] = c2s[wc + 16 * j + 4 * l4 + r];

#pragma unroll
    for (int i = 0; i < 4; ++i) {
        int rl = wr + 16 * i + l15;
        bool rv = vldp[rl] != 0;
        float z2v = z2s[rl];
        float s = 0.f;
        unsigned short* Ep = Eg + (size_t)(r0 + rl) * NCODES + c0 + wc + l4 * 4;
#pragma unroll
        for (int j = 0; j < 4; ++j) {
            float e[4];
#pragma unroll
            for (int r = 0; r < 4; ++r) {
                float d2 = z2v + c2r[j][r] - 2.0f * acc[i][j][r];
                float d = sqrtf(fmaxf(d2, 1e-12f));
                e[r] = __expf(SHIFTC - d);
                s += e[r];
            }
            if (rv) {
                unsigned h0 = __builtin_bit_cast(unsigned short, __float2bfloat16(e[0]));
                unsigned h1 = __builtin_bit_cast(unsigned short, __float2bfloat16(e[1]));
                unsigned h2 = __builtin_bit_cast(unsigned short, __float2bfloat16(e[2]));
                unsigned h3 = __builtin_bit_cast(unsigned short, __float2bfloat16(e[3]));
                uint2 o;
                o.x = h0 | (h1 << 16);
                o.y = h2 | (h3 << 16);
                *(uint2*)(Ep + 16 * j) = o;
            }
        }
        s += __shfl_xor(s, 16); s += __shfl_xor(s, 32);
        if (l4 == 0 && rv) atomicAdd(&Sg[r0 + rl], s);
    }

    // ---- panel completion: last of the 32 col-blocks scans the E panel --------
    __syncthreads();                       // drains all E stores + Sg atomics to L2
    if (tid == 0) {
        __threadfence();                   // release: L2 writeback to coherent point
        s_old = atomicAdd(&pcnt[blockIdx.y], 1);
    }
    __syncthreads();
    if (s_old != 31) return;

    __threadfence();                       // acquire: invalidate stale local L2
    float inv = 0.f;
    if (tid < 128) {
        int n = r0 + tid;
        if (n < NROWS) {
            int b = n / TT, t = n - b * TT;
            int nv = lengths[b] / stride_p[0];
            if (nv > TT) nv = TT;
            if (t < nv) inv = 1.0f / Sg[n];
        }
    }
    unsigned long long mb = __ballot(tid < 128 && inv != 0.f);  // per-wave mask
    if (tid < 128 && (tid & 63) == 0) wcnt[tid >> 6] = __popcll(mb);
    __syncthreads();
    if (tid < 128 && inv != 0.f) {
        int pos = __popcll(mb & ((1ull << (tid & 63)) - 1ull))
                + ((tid >> 6) ? wcnt[0] : 0);
        vrL[pos] = (unsigned char)tid;
        rsL[pos] = inv;
    }
    __syncthreads();
    int m = wcnt[0] + wcnt[1];

    // scan: 256 threads x 16 cols; rows 4-unrolled (8 uint4 loads in flight)
    int cc = tid * 16;
    const unsigned short* eb = Eg + (size_t)r0 * NCODES + cc;
    float a2[16];
#pragma unroll
    for (int q = 0; q < 16; ++q) a2[q] = 0.f;

#define ACC16(V0, V1, RN) do { \
    unsigned int _u[8] = {(V0).x, (V0).y, (V0).z, (V0).w, \
                          (V1).x, (V1).y, (V1).z, (V1).w}; \
    _Pragma("unroll") \
    for (int q = 0; q < 8; ++q) { \
        a2[2 * q]     += (RN) * __builtin_bit_cast(float, _u[q] << 16); \
        a2[2 * q + 1] += (RN) * __builtin_bit_cast(float, _u[q] & 0xffff0000u); \
    } \
} while (0)

    int i2 = 0;
    for (; i2 + 4 <= m; i2 += 4) {
        const unsigned short* p0 = eb + (size_t)vrL[i2]     * NCODES;
        const unsigned short* p1 = eb + (size_t)vrL[i2 + 1] * NCODES;
        const unsigned short* p2 = eb + (size_t)vrL[i2 + 2] * NCODES;
        const unsigned short* p3 = eb + (size_t)vrL[i2 + 3] * NCODES;
        uint4 a0 = *(const uint4*)p0, b0 = *(const uint4*)(p0 + 8);
        uint4 a1 = *(const uint4*)p1, b1 = *(const uint4*)(p1 + 8);
        uint4 a2v = *(const uint4*)p2, b2v = *(const uint4*)(p2 + 8);
        uint4 a3 = *(const uint4*)p3, b3 = *(const uint4*)(p3 + 8);
        ACC16(a0, b0, rsL[i2]);     ACC16(a1, b1, rsL[i2 + 1]);
        ACC16(a2v, b2v, rsL[i2 + 2]); ACC16(a3, b3, rsL[i2 + 3]);
    }
    for (; i2 < m; ++i2) {
        const unsigned short* p0 = eb + (size_t)vrL[i2] * NCODES;
        uint4 a0 = *(const uint4*)p0, b0 = *(const uint4*)(p0 + 8);
        ACC16(a0, b0, rsL[i2]);
    }
#undef ACC16

    float* outp = cdp + (size_t)(blockIdx.y & (NSLICE - 1)) * NCODES;
#pragma unroll
    for (int q = 0; q < 16; ++q) atomicAdd(&outp[cc + q], a2[q]);
}

// ---------------- fallback (small ws): two-pass GEMM (writes cdp slice 0) -------
template <int PASS>
__global__ __launch_bounds__(256, 2) void k_gemm(
    const unsigned short* __restrict__ zbf, const unsigned short* __restrict__ cbbf,
    const float* __restrict__ z2, const float* __restrict__ c2,
    const int* __restrict__ lengths, const int* __restrict__ stride_p,
    float* __restrict__ Sg, float* __restrict__ cd) {
    __shared__ unsigned short Asf[128 * 64];
    __shared__ unsigned short Bsf[128 * 64];
    __shared__ float z2s[128], c2s[128], rs[128];
    __shared__ int s_any;
    int tid = threadIdx.x;
    int r0 = blockIdx.y * 128, c0 = blockIdx.x * 128;
    if (tid == 0) s_any = 0;
    __syncthreads();
    if (tid < 128) {
        int n = r0 + tid;
        int valid = 0;
        if (n < NROWS) {
            int b = n / TT, t = n - b * TT;
            int stride = stride_p[0];
            int nv = lengths[b] / stride;
            if (nv > TT) nv = TT;
            valid = (t < nv);
        }
        if (valid) atomicOr(&s_any, 1);
        z2s[tid] = z2[r0 + tid];
        c2s[tid] = c2[c0 + tid];
        if (PASS == 2) rs[tid] = valid ? (1.0f / Sg[r0 + tid]) : 0.0f;
    }
    __syncthreads();
    if (!s_any) return;

    int wave = tid >> 6, lane = tid & 63;
    int l15 = lane & 15, l4 = lane >> 4;
    int wr = (wave >> 1) * 64, wc = (wave & 1) * 64;
    int srow = lane >> 3;
    int scg = (lane & 7) ^ srow;
    const unsigned short* ag = zbf + (size_t)(r0 + wave * 32 + srow) * DIM + scg * 8;
    const unsigned short* bg = cbbf + (size_t)(c0 + wave * 32 + srow) * DIM + scg * 8;
    unsigned short* al = Asf + (wave * 32) * 64;
    unsigned short* bl = Bsf + (wave * 32) * 64;

    floatx4 acc[4][4];
    const floatx4 zero = {0.f, 0.f, 0.f, 0.f};
#pragma unroll
    for (int i = 0; i < 4; ++i)
#pragma unroll
        for (int j = 0; j < 4; ++j) acc[i][j] = zero;
    int sw = l15 & 7;
    for (int kc = 0; kc < 8; ++kc) {
#pragma unroll
        for (int q = 0; q < 4; ++q) {
            glds16(ag + (size_t)q * 8 * DIM + kc * 64, al + q * 8 * 64);
            glds16(bg + (size_t)q * 8 * DIM + kc * 64, bl + q * 8 * 64);
        }
        __syncthreads();
#pragma unroll
        for (int ks = 0; ks < 64; ks += 32) {
            int g = (ks >> 3) + l4;
            int pcg = g ^ sw;
            bf16x8 av[4], bvv[4];
#pragma unroll
            for (int i = 0; i < 4; ++i)
                av[i] = __builtin_bit_cast(bf16x8, *(const ushortx8*)&Asf[(wr + 16 * i + l15) * 64 + pcg * 8]);
#pragma unroll
            for (int j = 0; j < 4; ++j)
                bvv[j] = __builtin_bit_cast(bf16x8, *(const ushortx8*)&Bsf[(wc + 16 * j + l15) * 64 + pcg * 8]);
#pragma unroll
            for (int i = 0; i < 4; ++i)
#pragma unroll
                for (int j = 0; j < 4; ++j)
                    acc[i][j] = __builtin_amdgcn_mfma_f32_16x16x32_bf16(av[i], bvv[j], acc[i][j], 0, 0, 0);
        }
        __syncthreads();
    }
    if (PASS == 1) {
#pragma unroll
        for (int i = 0; i < 4; ++i) {
#pragma unroll
            for (int r = 0; r < 4; ++r) {
                int rl = wr + 16 * i + 4 * l4 + r;
                float z2v = z2s[rl];
                float s = 0.f;
#pragma unroll
                for (int j = 0; j < 4; ++j) {
                    int cl = wc + 16 * j + l15;
                    float d2 = z2v + c2s[cl] - 2.0f * acc[i][j][r];
                    float d = sqrtf(fmaxf(d2, 1e-12f));
                    s += __expf(SHIFTC - d);
                }
                s += __shfl_xor(s, 1); s += __shfl_xor(s, 2);
                s += __shfl_xor(s, 4); s += __shfl_xor(s, 8);
                if (l15 == 0) atomicAdd(&Sg[r0 + rl], s);
            }
        }
    } else {
#pragma unroll
        for (int j = 0; j < 4; ++j) {
            int cl = wc + 16 * j + l15;
            float c2v = c2s[cl];
            float cs = 0.f;
#pragma unroll
            for (int i = 0; i < 4; ++i) {
#pragma unroll
                for (int r = 0; r < 4; ++r) {
                    int rl = wr + 16 * i + 4 * l4 + r;
                    float d2 = z2s[rl] + c2v - 2.0f * acc[i][j][r];
                    float d = sqrtf(fmaxf(d2, 1e-12f));
                    cs += __expf(SHIFTC - d) * rs[rl];
                }
            }
            cs += __shfl_xor(cs, 16); cs += __shfl_xor(cs, 32);
            if (l4 == 0) atomicAdd(&cd[c0 + cl], cs);
        }
    }
}

// ---------------- finalize (2-stage, 16 blocks each) ----------------------------
__global__ __launch_bounds__(256) void k_red(float* __restrict__ cdp,
                                             float* __restrict__ tot) {
    int k = blockIdx.x * 256 + threadIdx.x;
    float v = 0.f;
#pragma unroll
    for (int s = 0; s < NSLICE; ++s) v += cdp[(size_t)s * NCODES + k];
    cdp[k] = v;
    float t = v;
#pragma unroll
    for (int off = 32; off >= 1; off >>= 1) t += __shfl_down(t, off);
    if ((threadIdx.x & 63) == 0) atomicAdd(tot, t);
}

__global__ __launch_bounds__(256) void k_ent(const float* __restrict__ cdp,
                                             const float* __restrict__ tot,
                                             float* __restrict__ out) {
    int k = blockIdx.x * 256 + threadIdx.x;
    float inv = 1.0f / (tot[0] + 1e-8f);
    float p = cdp[k] * inv;
    float e = p * __logf(p + 1e-8f);
#pragma unroll
    for (int off = 32; off >= 1; off >>= 1) e += __shfl_down(e, off);
    if ((threadIdx.x & 63) == 0)
        atomicAdd(out, e * (1.0f / __logf((float)NCODES)));
}

// ---------------- launcher ----------------
extern "C" void kernel_launch(void* const* d_in, const int* in_sizes, int n_in,
                              void* d_out, int out_size, void* d_ws, size_t ws_size,
                              hipStream_t stream) {
    const float* sf = (const float*)d_in[0];
    const float* cb = (const float*)d_in[1];
    const int* lengths = (const int*)d_in[2];
    const int* stride_p = (const int*)d_in[3];

    float* wsf = (float*)d_ws;
    float* Sg = wsf;                                     // NROWS_PAD
    float* cdp = Sg + NROWS_PAD;                         // NSLICE*NCODES
    float* tot = wsf + NZERO;                            // 1 scalar
    int* pcnt = (int*)(wsf + NZERO2);                    // ROW_TILES counters
    const size_t OFF_Z2 = NZERO3;
    const size_t OFF_C2 = OFF_Z2 + NROWS_PAD;
    const size_t OFF_ZB = (OFF_C2 + NCODES + 3) & ~(size_t)3;  // 16B-align bf16 region
    float* z2 = wsf + OFF_Z2;
    float* c2 = wsf + OFF_C2;
    unsigned short* zbf = (unsigned short*)(wsf + OFF_ZB);     // NROWS_PAD*DIM bf16
    unsigned short* cbbf = zbf + (size_t)NROWS_PAD * DIM;      // NCODES*DIM bf16
    unsigned short* Eg = cbbf + (size_t)NCODES * DIM;          // NROWS_PAD*NCODES bf16

    size_t need = OFF_ZB * 4
                + ((size_t)NROWS_PAD * DIM + (size_t)NCODES * DIM
                 + (size_t)NROWS_PAD * NCODES) * 2;

    k_prep<<<dim3(TBLKS + CBLKS), 256, 0, stream>>>(
        sf, cb, zbf, cbbf, z2, c2, Sg, (float*)d_out);
    if (ws_size >= need) {
        k_gemm1<<<dim3(NBLKX, ROW_TILES), 256, 0, stream>>>(
            zbf, cbbf, z2, c2, lengths, stride_p, Sg, Eg, pcnt, cdp);
    } else {
        k_gemm<1><<<dim3(NBLKX, ROW_TILES), 256, 0, stream>>>(zbf, cbbf, z2, c2, lengths, stride_p, Sg, cdp);
        k_gemm<2><<<dim3(NBLKX, ROW_TILES), 256, 0, stream>>>(zbf, cbbf, z2, c2, lengths, stride_p, Sg, cdp);
    }
    k_red<<<dim3(NCODES / 256), 256, 0, stream>>>(cdp, tot);
    k_ent<<<dim3(NCODES / 256), 256, 0, stream>>>(cdp, tot, (float*)d_out);
}

// Round 7
// 217.943 us; speedup vs baseline: 2.2638x; 2.2638x over previous
//
#include <hip/hip_runtime.h>
#include <hip/hip_bf16.h>

// ---------------- problem constants (fixed by setup_inputs) ----------------
#define NUM_B   16
#define DIM     512
#define TT      1500
#define NROWS   (NUM_B * TT)              // 24000
#define NCODES  4096
#define ROW_TILES ((NROWS + 127) / 128)   // 188
#define NROWS_PAD (ROW_TILES * 128)       // 24064
#define NSLICE  8                         // partial cd slices (atomic decontention)
#define SHIFTC  30.0f                     // exp shift: exp(SHIFT-d), cancels in softmax
#define NBLKX   (NCODES / 128)            // 32 col tiles
#define TBLKS   (NUM_B * 47)              // 752 transpose blocks (47 t-tiles of 32)
#define CBLKS   (NCODES / 4)              // 1024 cb blocks
#define NZERO   (NROWS_PAD + NSLICE * NCODES)   // Sg + cdp
#define NZERO2  (NZERO + 1)               // + tot scalar

typedef __bf16 bf16x8 __attribute__((ext_vector_type(8)));
typedef float  floatx4 __attribute__((ext_vector_type(4)));
typedef unsigned short ushortx8 __attribute__((ext_vector_type(8)));

// async global->LDS, 16B per lane; dest = wave-uniform base + lane*16
__device__ __forceinline__ void glds16(const void* g, void* l) {
    __builtin_amdgcn_global_load_lds(
        (__attribute__((address_space(1))) void*)(void*)g,
        (__attribute__((address_space(3))) void*)l, 16, 0, 0);
}

// ---------------- prep: transpose + z2 (register-accum) + cb + ws zeroing -------
__global__ __launch_bounds__(256) void k_prep(
    const float* __restrict__ sf, const float* __restrict__ cb,
    unsigned short* __restrict__ zbf, unsigned short* __restrict__ cbbf,
    float* __restrict__ z2, float* __restrict__ c2, float* __restrict__ zero0,
    float* __restrict__ outp) {
    int id = blockIdx.x, tid = threadIdx.x;
    if (id < TBLKS) {
        __shared__ float tile[32][257];
        int b = id / 47, t0 = (id % 47) * 32;
        int tl = tid & 31, dg = tid >> 5;       // phase 1: t lane, d group (8x32)
        int tr = tid >> 3, dgr = tid & 7;       // phase 2: 8 lanes per t-row
        int tg = t0 + tr;
        float ssq = 0.f;
        unsigned short* dst = zbf + (size_t)(b * TT + tg) * DIM;
#pragma unroll
        for (int half = 0; half < 2; ++half) {
            int dbase = half * 256;
            if (half) __syncthreads();          // drain phase-2 reads of prev half
            int t = t0 + tl;
            if (t < TT) {
                const float* src = sf + (size_t)(b * DIM + dbase + dg * 32) * TT + t;
#pragma unroll
                for (int k = 0; k < 32; ++k)
                    tile[tl][dg * 32 + k] = src[(size_t)k * TT];
            }
            __syncthreads();
            if (tg < TT) {
#pragma unroll
                for (int seg = 0; seg < 4; ++seg) {
                    int d0 = seg * 64 + dgr * 8;
                    unsigned int h[8];
#pragma unroll
                    for (int i2 = 0; i2 < 8; ++i2) {
                        __hip_bfloat16 hb = __float2bfloat16(tile[tr][d0 + i2]);
                        h[i2] = __builtin_bit_cast(unsigned short, hb);
                        float vb = __bfloat162float(hb);
                        ssq += vb * vb;
                    }
                    uint4 o;
                    o.x = h[0] | (h[1] << 16); o.y = h[2] | (h[3] << 16);
                    o.z = h[4] | (h[5] << 16); o.w = h[6] | (h[7] << 16);
                    *(uint4*)(dst + dbase + d0) = o;
                }
            }
        }
        // reduce over the 8 lanes sharing tr (lane bits 0..2)
        ssq += __shfl_xor(ssq, 1); ssq += __shfl_xor(ssq, 2); ssq += __shfl_xor(ssq, 4);
        if (dgr == 0 && tg < TT) z2[b * TT + tg] = ssq;
    } else {
        int ci = id - TBLKS;
        int gid = ci * 256 + tid;
        if (gid < NZERO2) zero0[gid] = 0.f;
        if (ci == 0 && tid == 0) outp[0] = 1.0f;
        int k = ci * 4 + (tid >> 6);
        int lane = tid & 63;
        const float4* src = (const float4*)(cb + (size_t)k * DIM + lane * 8);
        float4 a = src[0], b2 = src[1];
        float vals[8] = {a.x, a.y, a.z, a.w, b2.x, b2.y, b2.z, b2.w};
        float s = 0.f;
        unsigned int h[8];
#pragma unroll
        for (int i = 0; i < 8; ++i) {
            __hip_bfloat16 hb = __float2bfloat16(vals[i]);
            h[i] = __builtin_bit_cast(unsigned short, hb);
            float vb = __bfloat162float(hb);
            s += vb * vb;
        }
        uint4 o;
        o.x = h[0] | (h[1] << 16); o.y = h[2] | (h[3] << 16);
        o.z = h[4] | (h[5] << 16); o.w = h[6] | (h[7] << 16);
        *(uint4*)(cbbf + (size_t)k * DIM + lane * 8) = o;
#pragma unroll
        for (int off = 32; off >= 1; off >>= 1) s += __shfl_down(s, off);
        if (lane == 0) c2[k] = s;
    }
}

// ---------------- pass 1: GEMM + exp; accumulate S, store E bf16 ----------------
// Proven 128x128 2-phase structure; MFMA operands swapped (mfma(bv, av, acc) ->
// acc's 4 regs = 4 CONSECUTIVE codebook cols), packed 8B E-stores.
// Swapped C/D layout: row (n)  = wr + 16*i + (lane&15)
//                     col (k)  = wc + 16*j + (lane>>4)*4 + reg
__global__ __launch_bounds__(256, 2) void k_gemm1(
    const unsigned short* __restrict__ zbf, const unsigned short* __restrict__ cbbf,
    const float* __restrict__ z2, const float* __restrict__ c2,
    const int* __restrict__ lengths, const int* __restrict__ stride_p,
    float* __restrict__ Sg, unsigned short* __restrict__ Eg) {
    __shared__ unsigned short As[128 * 64];
    __shared__ unsigned short Bs[128 * 64];
    __shared__ float z2s[128], c2s[128];
    __shared__ unsigned char vldp[128];
    __shared__ int s_any;
    int tid = threadIdx.x;
    int r0 = blockIdx.y * 128, c0 = blockIdx.x * 128;
    if (tid == 0) s_any = 0;
    __syncthreads();
    if (tid < 128) {
        int n = r0 + tid;
        int valid = 0;
        if (n < NROWS) {
            int b = n / TT, t = n - b * TT;
            int stride = stride_p[0];
            int nv = lengths[b] / stride;
            if (nv > TT) nv = TT;
            valid = (t < nv);
        }
        if (valid) atomicOr(&s_any, 1);
        vldp[tid] = (unsigned char)valid;
        z2s[tid] = z2[r0 + tid];
        c2s[tid] = c2[c0 + tid];
    }
    __syncthreads();
    if (!s_any) return;   // fully-masked row tile: contributes nothing

    int wave = tid >> 6, lane = tid & 63;
    int l15 = lane & 15, l4 = lane >> 4;
    int wr = (wave >> 1) * 64, wc = (wave & 1) * 64;

    int srow = lane >> 3;
    int scg = (lane & 7) ^ srow;
    const unsigned short* ag = zbf + (size_t)(r0 + wave * 32 + srow) * DIM + scg * 8;
    const unsigned short* bg = cbbf + (size_t)(c0 + wave * 32 + srow) * DIM + scg * 8;
    unsigned short* al = As + (wave * 32) * 64;
    unsigned short* bl = Bs + (wave * 32) * 64;

    floatx4 acc[4][4];
    const floatx4 zero = {0.f, 0.f, 0.f, 0.f};
#pragma unroll
    for (int i = 0; i < 4; ++i)
#pragma unroll
        for (int j = 0; j < 4; ++j) acc[i][j] = zero;

    int sw = l15 & 7;

    for (int kc = 0; kc < 8; ++kc) {
#pragma unroll
        for (int q = 0; q < 4; ++q) {
            glds16(ag + (size_t)q * 8 * DIM + kc * 64, al + q * 8 * 64);
            glds16(bg + (size_t)q * 8 * DIM + kc * 64, bl + q * 8 * 64);
        }
        __syncthreads();
#pragma unroll
        for (int ks = 0; ks < 64; ks += 32) {
            int g = (ks >> 3) + l4;
            int pcg = g ^ sw;
            bf16x8 av[4], bv[4];
#pragma unroll
            for (int i = 0; i < 4; ++i)
                av[i] = __builtin_bit_cast(bf16x8,
                    *(const ushortx8*)&As[(wr + 16 * i + l15) * 64 + pcg * 8]);
#pragma unroll
            for (int j = 0; j < 4; ++j)
                bv[j] = __builtin_bit_cast(bf16x8,
                    *(const ushortx8*)&Bs[(wc + 16 * j + l15) * 64 + pcg * 8]);
#pragma unroll
            for (int i = 0; i < 4; ++i)
#pragma unroll
                for (int j = 0; j < 4; ++j)
                    acc[i][j] = __builtin_amdgcn_mfma_f32_16x16x32_bf16(bv[j], av[i], acc[i][j], 0, 0, 0);
        }
        __syncthreads();
    }

    // epilogue: e = exp(SHIFT - sqrt(z2+c2-2*dot)); S += row-sum; E[n][k] packed 8B
    float c2r[4][4];
#pragma unroll
    for (int j = 0; j < 4; ++j)
#pragma unroll
        for (int r = 0; r < 4; ++r)
            c2r[j][r] = c2s[wc + 16 * j + 4 * l4 + r];

#pragma unroll
    for (int i = 0; i < 4; ++i) {
        int rl = wr + 16 * i + l15;
        bool rv = vldp[rl] != 0;
        float z2v = z2s[rl];
        float s = 0.f;
        unsigned short* Ep = Eg + (size_t)(r0 + rl) * NCODES + c0 + wc + l4 * 4;
#pragma unroll
        for (int j = 0; j < 4; ++j) {
            float e[4];
#pragma unroll
            for (int r = 0; r < 4; ++r) {
                float d2 = z2v + c2r[j][r] - 2.0f * acc[i][j][r];
                float d = sqrtf(fmaxf(d2, 1e-12f));
                e[r] = __expf(SHIFTC - d);
                s += e[r];
            }
            if (rv) {
                unsigned h0 = __builtin_bit_cast(unsigned short, __float2bfloat16(e[0]));
                unsigned h1 = __builtin_bit_cast(unsigned short, __float2bfloat16(e[1]));
                unsigned h2 = __builtin_bit_cast(unsigned short, __float2bfloat16(e[2]));
                unsigned h3 = __builtin_bit_cast(unsigned short, __float2bfloat16(e[3]));
                uint2 o;
                o.x = h0 | (h1 << 16);
                o.y = h2 | (h3 << 16);
                *(uint2*)(Ep + 16 * j) = o;
            }
        }
        s += __shfl_xor(s, 16); s += __shfl_xor(s, 32);
        if (l4 == 0 && rv) atomicAdd(&Sg[r0 + rl], s);
    }
}

// ---------------- pass 2: memory-bound scan  cdp[slice][k] += E[n][k]/S[n] ------
// Grid (4, 376): 64 rows x 1024 cols per block (1504 blocks = 5.9 block-waves on
// 256 CUs; the old (2,376)=752 blocks left a ~33% tail-quantization idle).
// Valid rows ballot-compacted; 8 independent uint2 loads in flight per burst.
// Total atomics unchanged: 376 windows x 4096 cols = 1.54M.
__global__ __launch_bounds__(256) void k_scan(
    const unsigned short* __restrict__ Eg, const float* __restrict__ Sg,
    const int* __restrict__ lengths, const int* __restrict__ stride_p,
    float* __restrict__ cdp) {
    __shared__ float rs2[64];
    __shared__ unsigned char vrows[64];
    __shared__ int s_cnt;
    int tid = threadIdx.x;
    int r0 = blockIdx.y * 64;
    if (tid < 64) {                         // one wave: validity + compaction
        int valid = 0;
        float inv = 0.f;
        int n = r0 + tid;
        if (n < NROWS) {
            int b = n / TT, t = n - b * TT;
            int nv = lengths[b] / stride_p[0];
            if (nv > TT) nv = TT;
            valid = (t < nv);
            if (valid) inv = 1.0f / Sg[n];
        }
        unsigned long long mask = __ballot(valid);
        if (tid == 0) s_cnt = __popcll(mask);
        if (valid) {
            int pos = __popcll(mask & ((1ull << tid) - 1ull));
            vrows[pos] = (unsigned char)tid;
            rs2[pos] = inv;
        }
    }
    __syncthreads();
    int m = s_cnt;
    if (m == 0) return;

    int col0 = blockIdx.x * 1024 + tid * 4;
    const unsigned short* base = Eg + (size_t)r0 * NCODES + col0;
    float acc[4] = {0.f, 0.f, 0.f, 0.f};

#define ACC4(V, RN) do { \
    unsigned int _u[2] = {(V).x, (V).y}; \
    _Pragma("unroll") \
    for (int q = 0; q < 2; ++q) { \
        acc[2 * q]     += (RN) * __builtin_bit_cast(float, _u[q] << 16); \
        acc[2 * q + 1] += (RN) * __builtin_bit_cast(float, _u[q] & 0xffff0000u); \
    } \
} while (0)

    int i = 0;
    for (; i + 8 <= m; i += 8) {
        uint2 v0 = *(const uint2*)(base + (size_t)vrows[i]     * NCODES);
        uint2 v1 = *(const uint2*)(base + (size_t)vrows[i + 1] * NCODES);
        uint2 v2 = *(const uint2*)(base + (size_t)vrows[i + 2] * NCODES);
        uint2 v3 = *(const uint2*)(base + (size_t)vrows[i + 3] * NCODES);
        uint2 v4 = *(const uint2*)(base + (size_t)vrows[i + 4] * NCODES);
        uint2 v5 = *(const uint2*)(base + (size_t)vrows[i + 5] * NCODES);
        uint2 v6 = *(const uint2*)(base + (size_t)vrows[i + 6] * NCODES);
        uint2 v7 = *(const uint2*)(base + (size_t)vrows[i + 7] * NCODES);
        ACC4(v0, rs2[i]);     ACC4(v1, rs2[i + 1]);
        ACC4(v2, rs2[i + 2]); ACC4(v3, rs2[i + 3]);
        ACC4(v4, rs2[i + 4]); ACC4(v5, rs2[i + 5]);
        ACC4(v6, rs2[i + 6]); ACC4(v7, rs2[i + 7]);
    }
    for (; i < m; ++i) {
        uint2 v = *(const uint2*)(base + (size_t)vrows[i] * NCODES);
        ACC4(v, rs2[i]);
    }
#undef ACC4

    float* outp = cdp + (size_t)(blockIdx.y & (NSLICE - 1)) * NCODES;
#pragma unroll
    for (int t = 0; t < 4; ++t) atomicAdd(&outp[col0 + t], acc[t]);
}

// ---------------- fallback (small ws): two-pass GEMM (writes cdp slice 0) -------
template <int PASS>
__global__ __launch_bounds__(256, 2) void k_gemm(
    const unsigned short* __restrict__ zbf, const unsigned short* __restrict__ cbbf,
    const float* __restrict__ z2, const float* __restrict__ c2,
    const int* __restrict__ lengths, const int* __restrict__ stride_p,
    float* __restrict__ Sg, float* __restrict__ cd) {
    __shared__ unsigned short Asf[128 * 64];
    __shared__ unsigned short Bsf[128 * 64];
    __shared__ float z2s[128], c2s[128], rs[128];
    __shared__ int s_any;
    int tid = threadIdx.x;
    int r0 = blockIdx.y * 128, c0 = blockIdx.x * 128;
    if (tid == 0) s_any = 0;
    __syncthreads();
    if (tid < 128) {
        int n = r0 + tid;
        int valid = 0;
        if (n < NROWS) {
            int b = n / TT, t = n - b * TT;
            int stride = stride_p[0];
            int nv = lengths[b] / stride;
            if (nv > TT) nv = TT;
            valid = (t < nv);
        }
        if (valid) atomicOr(&s_any, 1);
        z2s[tid] = z2[r0 + tid];
        c2s[tid] = c2[c0 + tid];
        if (PASS == 2) rs[tid] = valid ? (1.0f / Sg[r0 + tid]) : 0.0f;
    }
    __syncthreads();
    if (!s_any) return;

    int wave = tid >> 6, lane = tid & 63;
    int l15 = lane & 15, l4 = lane >> 4;
    int wr = (wave >> 1) * 64, wc = (wave & 1) * 64;
    int srow = lane >> 3;
    int scg = (lane & 7) ^ srow;
    const unsigned short* ag = zbf + (size_t)(r0 + wave * 32 + srow) * DIM + scg * 8;
    const unsigned short* bg = cbbf + (size_t)(c0 + wave * 32 + srow) * DIM + scg * 8;
    unsigned short* al = Asf + (wave * 32) * 64;
    unsigned short* bl = Bsf + (wave * 32) * 64;

    floatx4 acc[4][4];
    const floatx4 zero = {0.f, 0.f, 0.f, 0.f};
#pragma unroll
    for (int i = 0; i < 4; ++i)
#pragma unroll
        for (int j = 0; j < 4; ++j) acc[i][j] = zero;
    int sw = l15 & 7;
    for (int kc = 0; kc < 8; ++kc) {
#pragma unroll
        for (int q = 0; q < 4; ++q) {
            glds16(ag + (size_t)q * 8 * DIM + kc * 64, al + q * 8 * 64);
            glds16(bg + (size_t)q * 8 * DIM + kc * 64, bl + q * 8 * 64);
        }
        __syncthreads();
#pragma unroll
        for (int ks = 0; ks < 64; ks += 32) {
            int g = (ks >> 3) + l4;
            int pcg = g ^ sw;
            bf16x8 av[4], bvv[4];
#pragma unroll
            for (int i = 0; i < 4; ++i)
                av[i] = __builtin_bit_cast(bf16x8, *(const ushortx8*)&Asf[(wr + 16 * i + l15) * 64 + pcg * 8]);
#pragma unroll
            for (int j = 0; j < 4; ++j)
                bvv[j] = __builtin_bit_cast(bf16x8, *(const ushortx8*)&Bsf[(wc + 16 * j + l15) * 64 + pcg * 8]);
#pragma unroll
            for (int i = 0; i < 4; ++i)
#pragma unroll
                for (int j = 0; j < 4; ++j)
                    acc[i][j] = __builtin_amdgcn_mfma_f32_16x16x32_bf16(av[i], bvv[j], acc[i][j], 0, 0, 0);
        }
        __syncthreads();
    }
    if (PASS == 1) {
#pragma unroll
        for (int i = 0; i < 4; ++i) {
#pragma unroll
            for (int r = 0; r < 4; ++r) {
                int rl = wr + 16 * i + 4 * l4 + r;
                float z2v = z2s[rl];
                float s = 0.f;
#pragma unroll
                for (int j = 0; j < 4; ++j) {
                    int cl = wc + 16 * j + l15;
                    float d2 = z2v + c2s[cl] - 2.0f * acc[i][j][r];
                    float d = sqrtf(fmaxf(d2, 1e-12f));
                    s += __expf(SHIFTC - d);
                }
                s += __shfl_xor(s, 1); s += __shfl_xor(s, 2);
                s += __shfl_xor(s, 4); s += __shfl_xor(s, 8);
                if (l15 == 0) atomicAdd(&Sg[r0 + rl], s);
            }
        }
    } else {
#pragma unroll
        for (int j = 0; j < 4; ++j) {
            int cl = wc + 16 * j + l15;
            float c2v = c2s[cl];
            float cs = 0.f;
#pragma unroll
            for (int i = 0; i < 4; ++i) {
#pragma unroll
                for (int r = 0; r < 4; ++r) {
                    int rl = wr + 16 * i + 4 * l4 + r;
                    float d2 = z2s[rl] + c2v - 2.0f * acc[i][j][r];
                    float d = sqrtf(fmaxf(d2, 1e-12f));
                    cs += __expf(SHIFTC - d) * rs[rl];
                }
            }
            cs += __shfl_xor(cs, 16); cs += __shfl_xor(cs, 32);
            if (l4 == 0) atomicAdd(&cd[c0 + cl], cs);
        }
    }
}

// ---------------- finalize (2-stage, 16 blocks each) ----------------------------
__global__ __launch_bounds__(256) void k_red(float* __restrict__ cdp,
                                             float* __restrict__ tot) {
    int k = blockIdx.x * 256 + threadIdx.x;
    float v = 0.f;
#pragma unroll
    for (int s = 0; s < NSLICE; ++s) v += cdp[(size_t)s * NCODES + k];
    cdp[k] = v;
    float t = v;
#pragma unroll
    for (int off = 32; off >= 1; off >>= 1) t += __shfl_down(t, off);
    if ((threadIdx.x & 63) == 0) atomicAdd(tot, t);
}

__global__ __launch_bounds__(256) void k_ent(const float* __restrict__ cdp,
                                             const float* __restrict__ tot,
                                             float* __restrict__ out) {
    int k = blockIdx.x * 256 + threadIdx.x;
    float inv = 1.0f / (tot[0] + 1e-8f);
    float p = cdp[k] * inv;
    float e = p * __logf(p + 1e-8f);
#pragma unroll
    for (int off = 32; off >= 1; off >>= 1) e += __shfl_down(e, off);
    if ((threadIdx.x & 63) == 0)
        atomicAdd(out, e * (1.0f / __logf((float)NCODES)));
}

// ---------------- launcher ----------------
extern "C" void kernel_launch(void* const* d_in, const int* in_sizes, int n_in,
                              void* d_out, int out_size, void* d_ws, size_t ws_size,
                              hipStream_t stream) {
    const float* sf = (const float*)d_in[0];
    const float* cb = (const float*)d_in[1];
    const int* lengths = (const int*)d_in[2];
    const int* stride_p = (const int*)d_in[3];

    float* wsf = (float*)d_ws;
    float* Sg = wsf;                                     // NROWS_PAD
    float* cdp = Sg + NROWS_PAD;                         // NSLICE*NCODES
    float* tot = wsf + NZERO;                            // 1 scalar
    const size_t OFF_Z2 = NZERO2;
    const size_t OFF_C2 = OFF_Z2 + NROWS_PAD;
    const size_t OFF_ZB = (OFF_C2 + NCODES + 3) & ~(size_t)3;  // 16B-align bf16 region
    float* z2 = wsf + OFF_Z2;
    float* c2 = wsf + OFF_C2;
    unsigned short* zbf = (unsigned short*)(wsf + OFF_ZB);     // NROWS_PAD*DIM bf16
    unsigned short* cbbf = zbf + (size_t)NROWS_PAD * DIM;      // NCODES*DIM bf16
    unsigned short* Eg = cbbf + (size_t)NCODES * DIM;          // NROWS_PAD*NCODES bf16

    size_t need = OFF_ZB * 4
                + ((size_t)NROWS_PAD * DIM + (size_t)NCODES * DIM
                 + (size_t)NROWS_PAD * NCODES) * 2;

    k_prep<<<dim3(TBLKS + CBLKS), 256, 0, stream>>>(
        sf, cb, zbf, cbbf, z2, c2, Sg, (float*)d_out);
    if (ws_size >= need) {
        k_gemm1<<<dim3(NBLKX, ROW_TILES), 256, 0, stream>>>(
            zbf, cbbf, z2, c2, lengths, stride_p, Sg, Eg);
        k_scan<<<dim3(4, NROWS_PAD / 64), 256, 0, stream>>>(
            Eg, Sg, lengths, stride_p, cdp);
    } else {
        k_gemm<1><<<dim3(NBLKX, ROW_TILES), 256, 0, stream>>>(zbf, cbbf, z2, c2, lengths, stride_p, Sg, cdp);
        k_gemm<2><<<dim3(NBLKX, ROW_TILES), 256, 0, stream>>>(zbf, cbbf, z2, c2, lengths, stride_p, Sg, cdp);
    }
    k_red<<<dim3(NCODES / 256), 256, 0, stream>>>(cdp, tot);
    k_ent<<<dim3(NCODES / 256), 256, 0, stream>>>(cdp, tot, (float*)d_out);
}

// Round 8
// 217.253 us; speedup vs baseline: 2.2710x; 1.0032x over previous
//
#include <hip/hip_runtime.h>
#include <hip/hip_bf16.h>

// ---------------- problem constants (fixed by setup_inputs) ----------------
#define NUM_B   16
#define DIM     512
#define TT      1500
#define NROWS   (NUM_B * TT)              // 24000
#define NCODES  4096
#define ROW_TILES ((NROWS + 127) / 128)   // 188
#define NROWS_PAD (ROW_TILES * 128)       // 24064
#define NSLICE  8                         // partial cd slices (atomic decontention)
#define SHIFTC  30.0f                     // exp shift: exp(SHIFT-d), cancels in softmax
#define NBLKX   (NCODES / 128)            // 32 col tiles
#define TBLKS   (NUM_B * 47)              // 752 transpose blocks (47 t-tiles of 32)
#define CBLKS   (NCODES / 4)              // 1024 cb blocks
#define NZERO   (NROWS_PAD + NSLICE * NCODES)   // Sg + cdp
#define NZERO2  (NZERO + 1)               // + tot scalar
#define RPB     188                       // rows per scan block (NROWS_PAD/128)

typedef __bf16 bf16x8 __attribute__((ext_vector_type(8)));
typedef float  floatx4 __attribute__((ext_vector_type(4)));
typedef unsigned short ushortx8 __attribute__((ext_vector_type(8)));

// async global->LDS, 16B per lane; dest = wave-uniform base + lane*16
__device__ __forceinline__ void glds16(const void* g, void* l) {
    __builtin_amdgcn_global_load_lds(
        (__attribute__((address_space(1))) void*)(void*)g,
        (__attribute__((address_space(3))) void*)l, 16, 0, 0);
}

// ---------------- prep: transpose + z2 (register-accum) + cb + ws zeroing -------
__global__ __launch_bounds__(256) void k_prep(
    const float* __restrict__ sf, const float* __restrict__ cb,
    unsigned short* __restrict__ zbf, unsigned short* __restrict__ cbbf,
    float* __restrict__ z2, float* __restrict__ c2, float* __restrict__ zero0,
    float* __restrict__ outp) {
    int id = blockIdx.x, tid = threadIdx.x;
    if (id < TBLKS) {
        __shared__ float tile[32][257];
        int b = id / 47, t0 = (id % 47) * 32;
        int tl = tid & 31, dg = tid >> 5;       // phase 1: t lane, d group (8x32)
        int tr = tid >> 3, dgr = tid & 7;       // phase 2: 8 lanes per t-row
        int tg = t0 + tr;
        float ssq = 0.f;
        unsigned short* dst = zbf + (size_t)(b * TT + tg) * DIM;
#pragma unroll
        for (int half = 0; half < 2; ++half) {
            int dbase = half * 256;
            if (half) __syncthreads();          // drain phase-2 reads of prev half
            int t = t0 + tl;
            if (t < TT) {
                const float* src = sf + (size_t)(b * DIM + dbase + dg * 32) * TT + t;
#pragma unroll
                for (int k = 0; k < 32; ++k)
                    tile[tl][dg * 32 + k] = src[(size_t)k * TT];
            }
            __syncthreads();
            if (tg < TT) {
#pragma unroll
                for (int seg = 0; seg < 4; ++seg) {
                    int d0 = seg * 64 + dgr * 8;
                    unsigned int h[8];
#pragma unroll
                    for (int i2 = 0; i2 < 8; ++i2) {
                        __hip_bfloat16 hb = __float2bfloat16(tile[tr][d0 + i2]);
                        h[i2] = __builtin_bit_cast(unsigned short, hb);
                        float vb = __bfloat162float(hb);
                        ssq += vb * vb;
                    }
                    uint4 o;
                    o.x = h[0] | (h[1] << 16); o.y = h[2] | (h[3] << 16);
                    o.z = h[4] | (h[5] << 16); o.w = h[6] | (h[7] << 16);
                    *(uint4*)(dst + dbase + d0) = o;
                }
            }
        }
        // reduce over the 8 lanes sharing tr (lane bits 0..2)
        ssq += __shfl_xor(ssq, 1); ssq += __shfl_xor(ssq, 2); ssq += __shfl_xor(ssq, 4);
        if (dgr == 0 && tg < TT) z2[b * TT + tg] = ssq;
    } else {
        int ci = id - TBLKS;
        int gid = ci * 256 + tid;
        if (gid < NZERO2) zero0[gid] = 0.f;
        if (ci == 0 && tid == 0) outp[0] = 1.0f;
        int k = ci * 4 + (tid >> 6);
        int lane = tid & 63;
        const float4* src = (const float4*)(cb + (size_t)k * DIM + lane * 8);
        float4 a = src[0], b2 = src[1];
        float vals[8] = {a.x, a.y, a.z, a.w, b2.x, b2.y, b2.z, b2.w};
        float s = 0.f;
        unsigned int h[8];
#pragma unroll
        for (int i = 0; i < 8; ++i) {
            __hip_bfloat16 hb = __float2bfloat16(vals[i]);
            h[i] = __builtin_bit_cast(unsigned short, hb);
            float vb = __bfloat162float(hb);
            s += vb * vb;
        }
        uint4 o;
        o.x = h[0] | (h[1] << 16); o.y = h[2] | (h[3] << 16);
        o.z = h[4] | (h[5] << 16); o.w = h[6] | (h[7] << 16);
        *(uint4*)(cbbf + (size_t)k * DIM + lane * 8) = o;
#pragma unroll
        for (int off = 32; off >= 1; off >>= 1) s += __shfl_down(s, off);
        if (lane == 0) c2[k] = s;
    }
}

// ---------------- pass 1: GEMM + exp; accumulate S, store E bf16 ----------------
// Proven 128x128 2-phase structure; MFMA operands swapped (mfma(bv, av, acc) ->
// acc's 4 regs = 4 CONSECUTIVE codebook cols), packed 8B E-stores.
// Swapped C/D layout: row (n)  = wr + 16*i + (lane&15)
//                     col (k)  = wc + 16*j + (lane>>4)*4 + reg
__global__ __launch_bounds__(256, 2) void k_gemm1(
    const unsigned short* __restrict__ zbf, const unsigned short* __restrict__ cbbf,
    const float* __restrict__ z2, const float* __restrict__ c2,
    const int* __restrict__ lengths, const int* __restrict__ stride_p,
    float* __restrict__ Sg, unsigned short* __restrict__ Eg) {
    __shared__ unsigned short As[128 * 64];
    __shared__ unsigned short Bs[128 * 64];
    __shared__ float z2s[128], c2s[128];
    __shared__ unsigned char vldp[128];
    __shared__ int s_any;
    int tid = threadIdx.x;
    int r0 = blockIdx.y * 128, c0 = blockIdx.x * 128;
    if (tid == 0) s_any = 0;
    __syncthreads();
    if (tid < 128) {
        int n = r0 + tid;
        int valid = 0;
        if (n < NROWS) {
            int b = n / TT, t = n - b * TT;
            int stride = stride_p[0];
            int nv = lengths[b] / stride;
            if (nv > TT) nv = TT;
            valid = (t < nv);
        }
        if (valid) atomicOr(&s_any, 1);
        vldp[tid] = (unsigned char)valid;
        z2s[tid] = z2[r0 + tid];
        c2s[tid] = c2[c0 + tid];
    }
    __syncthreads();
    if (!s_any) return;   // fully-masked row tile: contributes nothing

    int wave = tid >> 6, lane = tid & 63;
    int l15 = lane & 15, l4 = lane >> 4;
    int wr = (wave >> 1) * 64, wc = (wave & 1) * 64;

    int srow = lane >> 3;
    int scg = (lane & 7) ^ srow;
    const unsigned short* ag = zbf + (size_t)(r0 + wave * 32 + srow) * DIM + scg * 8;
    const unsigned short* bg = cbbf + (size_t)(c0 + wave * 32 + srow) * DIM + scg * 8;
    unsigned short* al = As + (wave * 32) * 64;
    unsigned short* bl = Bs + (wave * 32) * 64;

    floatx4 acc[4][4];
    const floatx4 zero = {0.f, 0.f, 0.f, 0.f};
#pragma unroll
    for (int i = 0; i < 4; ++i)
#pragma unroll
        for (int j = 0; j < 4; ++j) acc[i][j] = zero;

    int sw = l15 & 7;

    for (int kc = 0; kc < 8; ++kc) {
#pragma unroll
        for (int q = 0; q < 4; ++q) {
            glds16(ag + (size_t)q * 8 * DIM + kc * 64, al + q * 8 * 64);
            glds16(bg + (size_t)q * 8 * DIM + kc * 64, bl + q * 8 * 64);
        }
        __syncthreads();
#pragma unroll
        for (int ks = 0; ks < 64; ks += 32) {
            int g = (ks >> 3) + l4;
            int pcg = g ^ sw;
            bf16x8 av[4], bv[4];
#pragma unroll
            for (int i = 0; i < 4; ++i)
                av[i] = __builtin_bit_cast(bf16x8,
                    *(const ushortx8*)&As[(wr + 16 * i + l15) * 64 + pcg * 8]);
#pragma unroll
            for (int j = 0; j < 4; ++j)
                bv[j] = __builtin_bit_cast(bf16x8,
                    *(const ushortx8*)&Bs[(wc + 16 * j + l15) * 64 + pcg * 8]);
#pragma unroll
            for (int i = 0; i < 4; ++i)
#pragma unroll
                for (int j = 0; j < 4; ++j)
                    acc[i][j] = __builtin_amdgcn_mfma_f32_16x16x32_bf16(bv[j], av[i], acc[i][j], 0, 0, 0);
        }
        __syncthreads();
    }

    // epilogue: e = exp(SHIFT - sqrt(z2+c2-2*dot)); S += row-sum; E[n][k] packed 8B
    float c2r[4][4];
#pragma unroll
    for (int j = 0; j < 4; ++j)
#pragma unroll
        for (int r = 0; r < 4; ++r)
            c2r[j][r] = c2s[wc + 16 * j + 4 * l4 + r];

#pragma unroll
    for (int i = 0; i < 4; ++i) {
        int rl = wr + 16 * i + l15;
        bool rv = vldp[rl] != 0;
        float z2v = z2s[rl];
        float s = 0.f;
        unsigned short* Ep = Eg + (size_t)(r0 + rl) * NCODES + c0 + wc + l4 * 4;
#pragma unroll
        for (int j = 0; j < 4; ++j) {
            float e[4];
#pragma unroll
            for (int r = 0; r < 4; ++r) {
                float d2 = z2v + c2r[j][r] - 2.0f * acc[i][j][r];
                float d = sqrtf(fmaxf(d2, 1e-12f));
                e[r] = __expf(SHIFTC - d);
                s += e[r];
            }
            if (rv) {
                unsigned h0 = __builtin_bit_cast(unsigned short, __float2bfloat16(e[0]));
                unsigned h1 = __builtin_bit_cast(unsigned short, __float2bfloat16(e[1]));
                unsigned h2 = __builtin_bit_cast(unsigned short, __float2bfloat16(e[2]));
                unsigned h3 = __builtin_bit_cast(unsigned short, __float2bfloat16(e[3]));
                uint2 o;
                o.x = h0 | (h1 << 16);
                o.y = h2 | (h3 << 16);
                *(uint2*)(Ep + 16 * j) = o;
            }
        }
        s += __shfl_xor(s, 16); s += __shfl_xor(s, 32);
        if (l4 == 0 && rv) atomicAdd(&Sg[r0 + rl], s);
    }
}

// ---------------- pass 2: memory-bound scan  cdp[slice][k] += E[n][k]/S[n] ------
// Grid (4, 128): 512 blocks = exactly 2 per CU (zero tail quantization).
// Block (x,y) owns cols x*1024+[0,1024) and rows {y + 128*j, j<188} -- row
// interleaving makes every block sample all 16 batches, so valid-row counts
// are balanced (~94 each). Valid j's ballot-compacted once; 8-deep independent
// uint2 loads. Endgame atomics: 512 blocks x 1024 cols = 524K (was 1.54M).
__global__ __launch_bounds__(256) void k_scan(
    const unsigned short* __restrict__ Eg, const float* __restrict__ Sg,
    const int* __restrict__ lengths, const int* __restrict__ stride_p,
    float* __restrict__ cdp) {
    __shared__ float rs2[RPB];
    __shared__ unsigned char vrows[RPB];
    __shared__ int wtot[4];
    int tid = threadIdx.x;
    int y0 = blockIdx.y;                    // 0..127
    int lane = tid & 63, wv = tid >> 6;

    int valid = 0;
    float inv = 0.f;
    if (tid < RPB) {
        int n = y0 + 128 * tid;
        if (n < NROWS) {
            int b = n / TT, t = n - b * TT;
            int nv = lengths[b] / stride_p[0];
            if (nv > TT) nv = TT;
            if (t < nv) { valid = 1; inv = 1.0f / Sg[n]; }
        }
    }
    unsigned long long mask = __ballot(valid);
    if (lane == 0) wtot[wv] = __popcll(mask);
    __syncthreads();
    int base = 0;
#pragma unroll
    for (int w = 0; w < 4; ++w) if (w < wv) base += wtot[w];
    if (valid) {
        int pos = base + __popcll(mask & ((1ull << lane) - 1ull));
        vrows[pos] = (unsigned char)tid;    // stores j (0..187)
        rs2[pos] = inv;
    }
    __syncthreads();
    int m = wtot[0] + wtot[1] + wtot[2] + wtot[3];
    if (m == 0) return;

    int col0 = blockIdx.x * 1024 + tid * 4;
    const unsigned short* base_e = Eg + col0;
    float acc[4] = {0.f, 0.f, 0.f, 0.f};

#define ACC4(V, RN) do { \
    unsigned int _u[2] = {(V).x, (V).y}; \
    _Pragma("unroll") \
    for (int q = 0; q < 2; ++q) { \
        acc[2 * q]     += (RN) * __builtin_bit_cast(float, _u[q] << 16); \
        acc[2 * q + 1] += (RN) * __builtin_bit_cast(float, _u[q] & 0xffff0000u); \
    } \
} while (0)

#define ROWP(I) (base_e + (size_t)(y0 + 128 * (int)vrows[I]) * NCODES)
    int i = 0;
    for (; i + 8 <= m; i += 8) {
        uint2 v0 = *(const uint2*)ROWP(i);
        uint2 v1 = *(const uint2*)ROWP(i + 1);
        uint2 v2 = *(const uint2*)ROWP(i + 2);
        uint2 v3 = *(const uint2*)ROWP(i + 3);
        uint2 v4 = *(const uint2*)ROWP(i + 4);
        uint2 v5 = *(const uint2*)ROWP(i + 5);
        uint2 v6 = *(const uint2*)ROWP(i + 6);
        uint2 v7 = *(const uint2*)ROWP(i + 7);
        ACC4(v0, rs2[i]);     ACC4(v1, rs2[i + 1]);
        ACC4(v2, rs2[i + 2]); ACC4(v3, rs2[i + 3]);
        ACC4(v4, rs2[i + 4]); ACC4(v5, rs2[i + 5]);
        ACC4(v6, rs2[i + 6]); ACC4(v7, rs2[i + 7]);
    }
    for (; i < m; ++i) {
        uint2 v = *(const uint2*)ROWP(i);
        ACC4(v, rs2[i]);
    }
#undef ROWP
#undef ACC4

    float* outp = cdp + (size_t)(blockIdx.y & (NSLICE - 1)) * NCODES;
#pragma unroll
    for (int t = 0; t < 4; ++t) atomicAdd(&outp[col0 + t], acc[t]);
}

// ---------------- fallback (small ws): two-pass GEMM (writes cdp slice 0) -------
template <int PASS>
__global__ __launch_bounds__(256, 2) void k_gemm(
    const unsigned short* __restrict__ zbf, const unsigned short* __restrict__ cbbf,
    const float* __restrict__ z2, const float* __restrict__ c2,
    const int* __restrict__ lengths, const int* __restrict__ stride_p,
    float* __restrict__ Sg, float* __restrict__ cd) {
    __shared__ unsigned short Asf[128 * 64];
    __shared__ unsigned short Bsf[128 * 64];
    __shared__ float z2s[128], c2s[128], rs[128];
    __shared__ int s_any;
    int tid = threadIdx.x;
    int r0 = blockIdx.y * 128, c0 = blockIdx.x * 128;
    if (tid == 0) s_any = 0;
    __syncthreads();
    if (tid < 128) {
        int n = r0 + tid;
        int valid = 0;
        if (n < NROWS) {
            int b = n / TT, t = n - b * TT;
            int stride = stride_p[0];
            int nv = lengths[b] / stride;
            if (nv > TT) nv = TT;
            valid = (t < nv);
        }
        if (valid) atomicOr(&s_any, 1);
        z2s[tid] = z2[r0 + tid];
        c2s[tid] = c2[c0 + tid];
        if (PASS == 2) rs[tid] = valid ? (1.0f / Sg[r0 + tid]) : 0.0f;
    }
    __syncthreads();
    if (!s_any) return;

    int wave = tid >> 6, lane = tid & 63;
    int l15 = lane & 15, l4 = lane >> 4;
    int wr = (wave >> 1) * 64, wc = (wave & 1) * 64;
    int srow = lane >> 3;
    int scg = (lane & 7) ^ srow;
    const unsigned short* ag = zbf + (size_t)(r0 + wave * 32 + srow) * DIM + scg * 8;
    const unsigned short* bg = cbbf + (size_t)(c0 + wave * 32 + srow) * DIM + scg * 8;
    unsigned short* al = Asf + (wave * 32) * 64;
    unsigned short* bl = Bsf + (wave * 32) * 64;

    floatx4 acc[4][4];
    const floatx4 zero = {0.f, 0.f, 0.f, 0.f};
#pragma unroll
    for (int i = 0; i < 4; ++i)
#pragma unroll
        for (int j = 0; j < 4; ++j) acc[i][j] = zero;
    int sw = l15 & 7;
    for (int kc = 0; kc < 8; ++kc) {
#pragma unroll
        for (int q = 0; q < 4; ++q) {
            glds16(ag + (size_t)q * 8 * DIM + kc * 64, al + q * 8 * 64);
            glds16(bg + (size_t)q * 8 * DIM + kc * 64, bl + q * 8 * 64);
        }
        __syncthreads();
#pragma unroll
        for (int ks = 0; ks < 64; ks += 32) {
            int g = (ks >> 3) + l4;
            int pcg = g ^ sw;
            bf16x8 av[4], bvv[4];
#pragma unroll
            for (int i = 0; i < 4; ++i)
                av[i] = __builtin_bit_cast(bf16x8, *(const ushortx8*)&Asf[(wr + 16 * i + l15) * 64 + pcg * 8]);
#pragma unroll
            for (int j = 0; j < 4; ++j)
                bvv[j] = __builtin_bit_cast(bf16x8, *(const ushortx8*)&Bsf[(wc + 16 * j + l15) * 64 + pcg * 8]);
#pragma unroll
            for (int i = 0; i < 4; ++i)
#pragma unroll
                for (int j = 0; j < 4; ++j)
                    acc[i][j] = __builtin_amdgcn_mfma_f32_16x16x32_bf16(av[i], bvv[j], acc[i][j], 0, 0, 0);
        }
        __syncthreads();
    }
    if (PASS == 1) {
#pragma unroll
        for (int i = 0; i < 4; ++i) {
#pragma unroll
            for (int r = 0; r < 4; ++r) {
                int rl = wr + 16 * i + 4 * l4 + r;
                float z2v = z2s[rl];
                float s = 0.f;
#pragma unroll
                for (int j = 0; j < 4; ++j) {
                    int cl = wc + 16 * j + l15;
                    float d2 = z2v + c2s[cl] - 2.0f * acc[i][j][r];
                    float d = sqrtf(fmaxf(d2, 1e-12f));
                    s += __expf(SHIFTC - d);
                }
                s += __shfl_xor(s, 1); s += __shfl_xor(s, 2);
                s += __shfl_xor(s, 4); s += __shfl_xor(s, 8);
                if (l15 == 0) atomicAdd(&Sg[r0 + rl], s);
            }
        }
    } else {
#pragma unroll
        for (int j = 0; j < 4; ++j) {
            int cl = wc + 16 * j + l15;
            float c2v = c2s[cl];
            float cs = 0.f;
#pragma unroll
            for (int i = 0; i < 4; ++i) {
#pragma unroll
                for (int r = 0; r < 4; ++r) {
                    int rl = wr + 16 * i + 4 * l4 + r;
                    float d2 = z2s[rl] + c2v - 2.0f * acc[i][j][r];
                    float d = sqrtf(fmaxf(d2, 1e-12f));
                    cs += __expf(SHIFTC - d) * rs[rl];
                }
            }
            cs += __shfl_xor(cs, 16); cs += __shfl_xor(cs, 32);
            if (l4 == 0) atomicAdd(&cd[c0 + cl], cs);
        }
    }
}

// ---------------- finalize (2-stage, 16 blocks each) ----------------------------
__global__ __launch_bounds__(256) void k_red(float* __restrict__ cdp,
                                             float* __restrict__ tot) {
    int k = blockIdx.x * 256 + threadIdx.x;
    float v = 0.f;
#pragma unroll
    for (int s = 0; s < NSLICE; ++s) v += cdp[(size_t)s * NCODES + k];
    cdp[k] = v;
    float t = v;
#pragma unroll
    for (int off = 32; off >= 1; off >>= 1) t += __shfl_down(t, off);
    if ((threadIdx.x & 63) == 0) atomicAdd(tot, t);
}

__global__ __launch_bounds__(256) void k_ent(const float* __restrict__ cdp,
                                             const float* __restrict__ tot,
                                             float* __restrict__ out) {
    int k = blockIdx.x * 256 + threadIdx.x;
    float inv = 1.0f / (tot[0] + 1e-8f);
    float p = cdp[k] * inv;
    float e = p * __logf(p + 1e-8f);
#pragma unroll
    for (int off = 32; off >= 1; off >>= 1) e += __shfl_down(e, off);
    if ((threadIdx.x & 63) == 0)
        atomicAdd(out, e * (1.0f / __logf((float)NCODES)));
}

// ---------------- launcher ----------------
extern "C" void kernel_launch(void* const* d_in, const int* in_sizes, int n_in,
                              void* d_out, int out_size, void* d_ws, size_t ws_size,
                              hipStream_t stream) {
    const float* sf = (const float*)d_in[0];
    const float* cb = (const float*)d_in[1];
    const int* lengths = (const int*)d_in[2];
    const int* stride_p = (const int*)d_in[3];

    float* wsf = (float*)d_ws;
    float* Sg = wsf;                                     // NROWS_PAD
    float* cdp = Sg + NROWS_PAD;                         // NSLICE*NCODES
    float* tot = wsf + NZERO;                            // 1 scalar
    const size_t OFF_Z2 = NZERO2;
    const size_t OFF_C2 = OFF_Z2 + NROWS_PAD;
    const size_t OFF_ZB = (OFF_C2 + NCODES + 3) & ~(size_t)3;  // 16B-align bf16 region
    float* z2 = wsf + OFF_Z2;
    float* c2 = wsf + OFF_C2;
    unsigned short* zbf = (unsigned short*)(wsf + OFF_ZB);     // NROWS_PAD*DIM bf16
    unsigned short* cbbf = zbf + (size_t)NROWS_PAD * DIM;      // NCODES*DIM bf16
    unsigned short* Eg = cbbf + (size_t)NCODES * DIM;          // NROWS_PAD*NCODES bf16

    size_t need = OFF_ZB * 4
                + ((size_t)NROWS_PAD * DIM + (size_t)NCODES * DIM
                 + (size_t)NROWS_PAD * NCODES) * 2;

    k_prep<<<dim3(TBLKS + CBLKS), 256, 0, stream>>>(
        sf, cb, zbf, cbbf, z2, c2, Sg, (float*)d_out);
    if (ws_size >= need) {
        k_gemm1<<<dim3(NBLKX, ROW_TILES), 256, 0, stream>>>(
            zbf, cbbf, z2, c2, lengths, stride_p, Sg, Eg);
        k_scan<<<dim3(4, 128), 256, 0, stream>>>(
            Eg, Sg, lengths, stride_p, cdp);
    } else {
        k_gemm<1><<<dim3(NBLKX, ROW_TILES), 256, 0, stream>>>(zbf, cbbf, z2, c2, lengths, stride_p, Sg, cdp);
        k_gemm<2><<<dim3(NBLKX, ROW_TILES), 256, 0, stream>>>(zbf, cbbf, z2, c2, lengths, stride_p, Sg, cdp);
    }
    k_red<<<dim3(NCODES / 256), 256, 0, stream>>>(cdp, tot);
    k_ent<<<dim3(NCODES / 256), 256, 0, stream>>>(cdp, tot, (float*)d_out);
}